// Round 1
// baseline (980.268 us; speedup 1.0000x reference)
//
#include <hip/hip_runtime.h>
#include <math.h>

// Sizes (fixed by the problem)
#define Hh 80
#define Ww 80
#define HW 6400
#define NB 4

// ---------------------------------------------------------------------------
// Weight transpose: src OIHW (CO, CI, kh, kw)  ->  dst [(ci*taps + t)][CO]
// (co-contiguous rows so conv staging loads are coalesced)
// ---------------------------------------------------------------------------
__global__ void wt_kernel(const float* __restrict__ src, float* __restrict__ dst,
                          int CO, int CI, int taps) {
    int idx = blockIdx.x * 256 + threadIdx.x;
    int total = CO * CI * taps;
    if (idx >= total) return;
    int co = idx % CO;
    int kt = idx / CO;           // kt = ci*taps + t
    int t  = kt % taps;
    int ci = kt / taps;
    dst[idx] = src[(co * CI + ci) * taps + t];
}

// ---------------------------------------------------------------------------
// 3x3 conv, pad=1, CO=128 total, CO_TILE=64 per block, spatial tile 8x8.
// grid: (10, 10, N*2)  block: 256
// ACT: 0 = none, 1 = leaky(0.1), 2 = 10*tanh
// wt layout: [(ci*9 + tap)][128]
// ---------------------------------------------------------------------------
template <int CI, int ACT>
__global__ __launch_bounds__(256) void conv3x3_kernel(
    const float* __restrict__ in, const float* __restrict__ wt,
    const float* __restrict__ bias, float* __restrict__ out) {
    const int tx = blockIdx.x, ty = blockIdx.y;
    const int n = blockIdx.z >> 1, cot = blockIdx.z & 1;
    const int x0 = tx * 8, y0 = ty * 8;
    const int t = threadIdx.x;
    const int sp_grp = t & 15;   // 4 consecutive spatial each
    const int co_grp = t >> 4;   // 4 consecutive co each
    const int r  = sp_grp >> 1;
    const int c0 = (sp_grp & 1) * 4;

    __shared__ float As[8 * 9 * 64];     // [kc][tap][co]
    __shared__ float Bs[8][10][10];      // [kc][y][x] with halo

    float acc[4][4];
#pragma unroll
    for (int i = 0; i < 4; ++i)
#pragma unroll
        for (int j = 0; j < 4; ++j) acc[i][j] = 0.f;

    const int KCH = CI / 8;
    for (int ch = 0; ch < KCH; ++ch) {
        const int ci0 = ch * 8;
        __syncthreads();
        // stage A (weights): 4608 elements, coalesced over co
        for (int i = t; i < 8 * 9 * 64; i += 256) {
            int j = i & 63;
            int kt = i >> 6;     // kc*9 + tap
            As[i] = wt[(ci0 * 9 + kt) * 128 + cot * 64 + j];
        }
        // stage B (input patch with halo): 800 elements
        for (int i = t; i < 800; i += 256) {
            int cc = i % 10;
            int rr = (i / 10) % 10;
            int kc = i / 100;
            int yy = y0 - 1 + rr, xx = x0 - 1 + cc;
            float v = 0.f;
            if (yy >= 0 && yy < Hh && xx >= 0 && xx < Ww)
                v = in[((size_t)(n * CI + ci0 + kc) * Hh + yy) * Ww + xx];
            Bs[kc][rr][cc] = v;
        }
        __syncthreads();
#pragma unroll
        for (int kc = 0; kc < 8; ++kc) {
#pragma unroll
            for (int dy = 0; dy < 3; ++dy) {
                const float* brow = &Bs[kc][r + dy][c0];
#pragma unroll
                for (int dx = 0; dx < 3; ++dx) {
                    float4 a = *(const float4*)&As[(kc * 9 + dy * 3 + dx) * 64 + co_grp * 4];
                    float av[4] = {a.x, a.y, a.z, a.w};
                    float bv[4] = {brow[dx], brow[dx + 1], brow[dx + 2], brow[dx + 3]};
#pragma unroll
                    for (int i = 0; i < 4; ++i)
#pragma unroll
                        for (int j = 0; j < 4; ++j)
                            acc[i][j] = fmaf(av[i], bv[j], acc[i][j]);
                }
            }
        }
    }

    // epilogue
    const int co_base = cot * 64 + co_grp * 4;
    const size_t ob = ((size_t)(n * 128 + co_base) * Hh + (y0 + r)) * Ww + x0 + c0;
#pragma unroll
    for (int i = 0; i < 4; ++i) {
        float bv = bias[co_base + i];
#pragma unroll
        for (int j = 0; j < 4; ++j) {
            float v = acc[i][j] + bv;
            if (ACT == 1) v = (v >= 0.f) ? v : 0.1f * v;
            else if (ACT == 2) v = 10.f * tanhf(v);
            out[ob + (size_t)i * HW + j] = v;
        }
    }
}

// ---------------------------------------------------------------------------
// 1x1 conv (GEMM 128x128 over spatial). grid: (100, N), block 256.
// wt layout: [ci][128co]. MODE 0: write v_s NHWC-16 ([nb][s][16]);
// MODE 1: write NCHW.
// ---------------------------------------------------------------------------
template <int MODE>
__global__ __launch_bounds__(256) void conv1x1_kernel(
    const float* __restrict__ in, const float* __restrict__ wt,
    const float* __restrict__ bias, float* __restrict__ out) {
    const int n = blockIdx.y;
    const int s0 = blockIdx.x * 64;
    const int t = threadIdx.x;
    const int sp_grp = t & 15;  // 4 spatial each
    const int co_grp = t >> 4;  // 8 co each

    __shared__ float Wl[16 * 128];
    __shared__ float Il[16 * 64];

    float acc[8][4];
#pragma unroll
    for (int i = 0; i < 8; ++i)
#pragma unroll
        for (int j = 0; j < 4; ++j) acc[i][j] = 0.f;

    for (int ch = 0; ch < 8; ++ch) {
        const int ci0 = ch * 16;
        __syncthreads();
        for (int i = t; i < 16 * 128; i += 256) Wl[i] = wt[ci0 * 128 + i];
        for (int i = t; i < 16 * 64; i += 256) {
            int ci = i >> 6, sp = i & 63;
            Il[i] = in[(size_t)(n * 128 + ci0 + ci) * HW + s0 + sp];
        }
        __syncthreads();
#pragma unroll
        for (int ci = 0; ci < 16; ++ci) {
            float4 a0 = *(const float4*)&Wl[ci * 128 + co_grp * 8];
            float4 a1 = *(const float4*)&Wl[ci * 128 + co_grp * 8 + 4];
            float4 b  = *(const float4*)&Il[ci * 64 + sp_grp * 4];
            float av[8] = {a0.x, a0.y, a0.z, a0.w, a1.x, a1.y, a1.z, a1.w};
            float bv[4] = {b.x, b.y, b.z, b.w};
#pragma unroll
            for (int i = 0; i < 8; ++i)
#pragma unroll
                for (int j = 0; j < 4; ++j)
                    acc[i][j] = fmaf(av[i], bv[j], acc[i][j]);
        }
    }

#pragma unroll
    for (int i = 0; i < 8; ++i) {
        const int co = co_grp * 8 + i;
        const float bv = bias[co];
        if (MODE == 0) {
            const int hd = co >> 4, dd = co & 15;
#pragma unroll
            for (int j = 0; j < 4; ++j) {
                int s = s0 + sp_grp * 4 + j;
                out[((size_t)(n * 8 + hd) * HW + s) * 16 + dd] = acc[i][j] + bv;
            }
        } else {
#pragma unroll
            for (int j = 0; j < 4; ++j)
                out[(size_t)(n * 128 + co) * HW + s0 + sp_grp * 4 + j] = acc[i][j] + bv;
        }
    }
}

// ---------------------------------------------------------------------------
// Deformable attention. grid: (400, 8, 4) = (site/16, head, n), block 256
// = 16 sites x 16 channels. v_s layout [nb][s][16]. offs NCHW (output of
// conv4 w/ 10*tanh). att written NCHW.
// ---------------------------------------------------------------------------
__global__ __launch_bounds__(256) void deform_attn_kernel(
    const float* __restrict__ v_s, const float* __restrict__ offs,
    const float* __restrict__ ref, float* __restrict__ att) {
    const int n = blockIdx.z, hd = blockIdx.y;
    const int s = blockIdx.x * 16 + (threadIdx.x >> 4);
    const int d = threadIdx.x & 15;
    const int nb = n * 8 + hd;

    const float cv = v_s[((size_t)nb * HW + s) * 16 + d];
    const float rx = ref[(size_t)(n * HW + s) * 2 + 0] * 80.f - 0.5f;
    const float ry = ref[(size_t)(n * HW + s) * 2 + 1] * 80.f - 0.5f;

    // o.reshape(N,8,8,H,W,2) flat-reshape semantics:
    // offsets[n,hd,p,y,x,c] = o4[n][hd*16+2p+e][2s+c - 6400e], e = (s>=3200)
    const int e = (s >= 3200) ? 1 : 0;
    const float* ob = offs + (size_t)(n * 128 + hd * 16 + e) * HW + (2 * s - e * HW);

    float sampled[8], score[8];
#pragma unroll
    for (int p = 0; p < 8; ++p) {
        const float ox = ob[(size_t)p * 2 * HW];
        const float oy = ob[(size_t)p * 2 * HW + 1];
        const float px = rx + ox;
        const float py = ry + oy;
        const float fx = floorf(px), fy = floorf(py);
        const int ix = (int)fx, iy = (int)fy;
        const float wx1 = px - fx, wy1 = py - fy;
        const float wx0 = 1.f - wx1, wy0 = 1.f - wy1;

        auto samp = [&](int xx, int yy) -> float {
            if (xx < 0 || xx >= Ww || yy < 0 || yy >= Hh) return 0.f;
            return v_s[((size_t)nb * HW + yy * Ww + xx) * 16 + d];
        };
        const float v00 = samp(ix, iy);
        const float v01 = samp(ix + 1, iy);
        const float v10 = samp(ix, iy + 1);
        const float v11 = samp(ix + 1, iy + 1);
        const float sv = v00 * (wx0 * wy0) + v01 * (wx1 * wy0) +
                         v10 * (wx0 * wy1) + v11 * (wx1 * wy1);
        sampled[p] = sv;
        float sc = sv * cv;
        sc += __shfl_xor(sc, 1);
        sc += __shfl_xor(sc, 2);
        sc += __shfl_xor(sc, 4);
        sc += __shfl_xor(sc, 8);
        score[p] = sc;
    }

    float m = score[0];
#pragma unroll
    for (int p = 1; p < 8; ++p) m = fmaxf(m, score[p]);
    float sum = 0.f, aw[8];
#pragma unroll
    for (int p = 0; p < 8; ++p) {
        aw[p] = __expf(score[p] - m);
        sum += aw[p];
    }
    const float inv = 1.f / sum;
    float o = 0.f;
#pragma unroll
    for (int p = 0; p < 8; ++p) o += aw[p] * sampled[p];
    o *= inv;

    att[(size_t)(n * 128 + hd * 16 + d) * HW + s] = o;
}

// ---------------------------------------------------------------------------
extern "C" void kernel_launch(void* const* d_in, const int* in_sizes, int n_in,
                              void* d_out, int out_size, void* d_ws, size_t ws_size,
                              hipStream_t stream) {
    const float* query = (const float*)d_in[0];
    const float* value = (const float*)d_in[1];
    const float* ref   = (const float*)d_in[2];
    const float* co_w1 = (const float*)d_in[3];
    const float* co_b1 = (const float*)d_in[4];
    const float* co_w2 = (const float*)d_in[5];
    const float* co_b2 = (const float*)d_in[6];
    const float* co_w3 = (const float*)d_in[7];
    const float* co_b3 = (const float*)d_in[8];
    const float* co_w4 = (const float*)d_in[9];
    const float* co_b4 = (const float*)d_in[10];
    const float* val_w = (const float*)d_in[11];
    const float* val_b = (const float*)d_in[12];
    const float* out_w = (const float*)d_in[13];
    const float* out_b = (const float*)d_in[14];

    float* ws = (float*)d_ws;
    size_t o = 0;
    float* wt1 = ws + o; o += 294912;   // 256*9*128
    float* wt2 = ws + o; o += 147456;   // 128*9*128
    float* wt3 = ws + o; o += 147456;
    float* wt4 = ws + o; o += 147456;
    float* wtv = ws + o; o += 16384;    // 128*128
    float* wto = ws + o; o += 16384;
    float* v_s  = ws + o; o += 3276800; // [32][6400][16]
    float* bufA = ws + o; o += 3276800;
    float* bufB = ws + o; o += 3276800;

    // weight transposes
    wt_kernel<<<(294912 + 255) / 256, 256, 0, stream>>>(co_w1, wt1, 128, 256, 9);
    wt_kernel<<<(147456 + 255) / 256, 256, 0, stream>>>(co_w2, wt2, 128, 128, 9);
    wt_kernel<<<(147456 + 255) / 256, 256, 0, stream>>>(co_w3, wt3, 128, 128, 9);
    wt_kernel<<<(147456 + 255) / 256, 256, 0, stream>>>(co_w4, wt4, 128, 128, 9);
    wt_kernel<<<(16384 + 255) / 256, 256, 0, stream>>>(val_w, wtv, 128, 128, 1);
    wt_kernel<<<(16384 + 255) / 256, 256, 0, stream>>>(out_w, wto, 128, 128, 1);

    // v = 1x1 conv(value) -> v_s (NHWC-16)
    conv1x1_kernel<0><<<dim3(100, NB), 256, 0, stream>>>(value, wtv, val_b, v_s);

    // offset conv stack
    conv3x3_kernel<256, 1><<<dim3(10, 10, NB * 2), 256, 0, stream>>>(query, wt1, co_b1, bufA);
    conv3x3_kernel<128, 1><<<dim3(10, 10, NB * 2), 256, 0, stream>>>(bufA, wt2, co_b2, bufB);
    conv3x3_kernel<128, 1><<<dim3(10, 10, NB * 2), 256, 0, stream>>>(bufB, wt3, co_b3, bufA);
    conv3x3_kernel<128, 2><<<dim3(10, 10, NB * 2), 256, 0, stream>>>(bufA, wt4, co_b4, bufB);

    // deformable attention -> bufA (NCHW)
    deform_attn_kernel<<<dim3(400, 8, NB), 256, 0, stream>>>(v_s, bufB, ref, bufA);

    // final 1x1 conv -> d_out (NCHW)
    conv1x1_kernel<1><<<dim3(100, NB), 256, 0, stream>>>(bufA, wto, out_b, (float*)d_out);
}

// Round 2
// 427.815 us; speedup vs baseline: 2.2913x; 2.2913x over previous
//
#include <hip/hip_runtime.h>
#include <math.h>

#define Hh 80
#define Ww 80
#define HW 6400
#define NB 4

typedef _Float16 half8 __attribute__((ext_vector_type(8)));
typedef _Float16 half4v __attribute__((ext_vector_type(4)));
typedef float f32x16 __attribute__((ext_vector_type(16)));

// ---------------------------------------------------------------------------
// Weight transpose for 1x1 convs: OIHW -> [ci][co]
// ---------------------------------------------------------------------------
__global__ void wt_kernel(const float* __restrict__ src, float* __restrict__ dst,
                          int CO, int CI, int taps) {
    int idx = blockIdx.x * 256 + threadIdx.x;
    int total = CO * CI * taps;
    if (idx >= total) return;
    int co = idx % CO;
    int kt = idx / CO;
    int t  = kt % taps;
    int ci = kt / taps;
    dst[idx] = src[(co * CI + ci) * taps + t];
}

// ---------------------------------------------------------------------------
// Pack 3x3 conv weights OIHW fp32 -> fp16 MFMA A-fragment blob:
// flat = ((((CT*NC + c)*9 + tap)*2 + h)*64 + lane)*8 + j
//   co = CT*32 + (lane&31);  ci = c*32 + h*16 + (lane>>5)*8 + j
// ---------------------------------------------------------------------------
__global__ void wblob_kernel(const float* __restrict__ src, _Float16* __restrict__ dst,
                             int CI) {
    int d = blockIdx.x * 256 + threadIdx.x;
    int NC = CI / 32;
    int total = 128 * CI * 9;
    if (d >= total) return;
    int j = d & 7;
    int l = (d >> 3) & 63;
    int h = (d >> 9) & 1;
    int rest = d >> 10;
    int tap = rest % 9;
    rest /= 9;
    int c = rest % NC;
    int CT = rest / NC;
    int co = CT * 32 + (l & 31);
    int ci = c * 32 + h * 16 + (l >> 5) * 8 + j;
    dst[d] = (_Float16)src[((size_t)co * CI + ci) * 9 + tap];
}

// ---------------------------------------------------------------------------
// MFMA implicit-GEMM 3x3 conv, pad=1.  M=co(128), N=spatial, K=(ci,tap).
// Block: 256 thr = 4 waves; tile 64co x 64sp (wave = one 32x32 MFMA tile).
// grid: (100 sp-tiles, 2 co-halves, N)
// IN_NCHW: input fp32 NCHW (conv1) else fp16 NHWC.
// ACT 1: leaky -> fp16 NHWC out.  ACT 2: 10*tanh -> fp32 NHWC out.
// ---------------------------------------------------------------------------
template <int CI, int ACT, bool IN_NCHW>
__global__ __launch_bounds__(256) void conv3x3_mfma(
    const void* __restrict__ inp, const _Float16* __restrict__ wblob,
    const float* __restrict__ bias, void* __restrict__ outp) {
    const int bx = blockIdx.x, ch = blockIdx.y, n = blockIdx.z;
    const int t = threadIdx.x;
    const int wv = t >> 6, l = t & 63;
    const int ct = wv >> 1;        // co-tile within half
    const int st = wv & 1;         // sp-tile
    const int s0 = bx * 64;
    const int lane31 = l & 31, lhalf = l >> 5;

    __shared__ _Float16 Bs[226 * 40];   // 32 ci + 8 pad per row

    const int sp_loc = st * 32 + lane31;     // 0..63
    const int sglob = s0 + sp_loc;
    const int x = sglob % 80;
    const bool mx0 = (x >= 1), mx2 = (x <= 78);

    f32x16 acc = {};

    const int CT = ch * 2 + ct;
    const int NC = CI / 32;
    const _Float16* wb = wblob + (size_t)CT * NC * 9 * 2 * 512 + l * 8;

    for (int c = 0; c < NC; ++c) {
        __syncthreads();
        if (IN_NCHW) {
            const float* in_f = (const float*)inp;
            for (int idx = t; idx < 226 * 32; idx += 256) {
                int r = idx % 226;
                int cc = idx / 226;
                int sg = s0 - 81 + r;
                float v = 0.f;
                if (sg >= 0 && sg < HW)
                    v = in_f[((size_t)n * CI + c * 32 + cc) * HW + sg];
                Bs[r * 40 + cc] = (_Float16)v;
            }
        } else {
            const _Float16* in_h = (const _Float16*)inp;
            for (int idx = t; idx < 226 * 4; idx += 256) {
                int r = idx >> 2, chunk = idx & 3;
                int sg = s0 - 81 + r;
                int4 v = {0, 0, 0, 0};
                if (sg >= 0 && sg < HW)
                    v = *(const int4*)(in_h + ((size_t)n * HW + sg) * CI + c * 32 + chunk * 8);
                *(int4*)(&Bs[r * 40 + chunk * 8]) = v;
            }
        }
        __syncthreads();

        const _Float16* wc = wb + (size_t)c * 9 * 2 * 512;
#pragma unroll
        for (int tap = 0; tap < 9; ++tap) {
            const int dy = tap / 3, dx = tap % 3;
            const int r = sp_loc + dy * 80 + dx;
            const bool ok = (dx == 0) ? mx0 : ((dx == 2) ? mx2 : true);
            const half8 zero8 = {};
#pragma unroll
            for (int h = 0; h < 2; ++h) {
                half8 afrag = *(const half8*)(wc + (tap * 2 + h) * 512);
                half8 bfrag = ok ? *(const half8*)(&Bs[r * 40 + h * 16 + lhalf * 8]) : zero8;
                acc = __builtin_amdgcn_mfma_f32_32x32x16_f16(afrag, bfrag, acc, 0, 0, 0);
            }
        }
    }

    // epilogue: D col(n=sp)=lane&31, row(m=co)=(reg&3)+8*(reg>>2)+4*(lane>>5)
    const int co_base = ch * 64 + ct * 32;
    const size_t rowbase = ((size_t)n * HW + sglob) * 128;
#pragma unroll
    for (int q = 0; q < 4; ++q) {
        const int co0 = co_base + 8 * q + 4 * lhalf;
        float v[4];
#pragma unroll
        for (int i = 0; i < 4; ++i) {
            float vv = acc[q * 4 + i] + bias[co0 + i];
            if (ACT == 1) vv = (vv >= 0.f) ? vv : 0.1f * vv;
            else vv = 10.f * tanhf(vv);
            v[i] = vv;
        }
        if (ACT == 1) {
            half4v hv = {(_Float16)v[0], (_Float16)v[1], (_Float16)v[2], (_Float16)v[3]};
            *(half4v*)((_Float16*)outp + rowbase + co0) = hv;
        } else {
            float4 fv = {v[0], v[1], v[2], v[3]};
            *(float4*)((float*)outp + rowbase + co0) = fv;
        }
    }
}

// ---------------------------------------------------------------------------
// 1x1 conv (GEMM 128x128 over spatial). grid: (100, N), block 256.
// wt layout: [ci][128co]. MODE 0: write v_s NHWC-16; MODE 1: write NCHW.
// ---------------------------------------------------------------------------
template <int MODE>
__global__ __launch_bounds__(256) void conv1x1_kernel(
    const float* __restrict__ in, const float* __restrict__ wt,
    const float* __restrict__ bias, float* __restrict__ out) {
    const int n = blockIdx.y;
    const int s0 = blockIdx.x * 64;
    const int t = threadIdx.x;
    const int sp_grp = t & 15;
    const int co_grp = t >> 4;

    __shared__ float Wl[16 * 128];
    __shared__ float Il[16 * 64];

    float acc[8][4];
#pragma unroll
    for (int i = 0; i < 8; ++i)
#pragma unroll
        for (int j = 0; j < 4; ++j) acc[i][j] = 0.f;

    for (int ch = 0; ch < 8; ++ch) {
        const int ci0 = ch * 16;
        __syncthreads();
        for (int i = t; i < 16 * 128; i += 256) Wl[i] = wt[ci0 * 128 + i];
        for (int i = t; i < 16 * 64; i += 256) {
            int ci = i >> 6, sp = i & 63;
            Il[i] = in[(size_t)(n * 128 + ci0 + ci) * HW + s0 + sp];
        }
        __syncthreads();
#pragma unroll
        for (int ci = 0; ci < 16; ++ci) {
            float4 a0 = *(const float4*)&Wl[ci * 128 + co_grp * 8];
            float4 a1 = *(const float4*)&Wl[ci * 128 + co_grp * 8 + 4];
            float4 b  = *(const float4*)&Il[ci * 64 + sp_grp * 4];
            float av[8] = {a0.x, a0.y, a0.z, a0.w, a1.x, a1.y, a1.z, a1.w};
            float bv[4] = {b.x, b.y, b.z, b.w};
#pragma unroll
            for (int i = 0; i < 8; ++i)
#pragma unroll
                for (int j = 0; j < 4; ++j)
                    acc[i][j] = fmaf(av[i], bv[j], acc[i][j]);
        }
    }

#pragma unroll
    for (int i = 0; i < 8; ++i) {
        const int co = co_grp * 8 + i;
        const float bv = bias[co];
        if (MODE == 0) {
            const int hd = co >> 4, dd = co & 15;
#pragma unroll
            for (int j = 0; j < 4; ++j) {
                int s = s0 + sp_grp * 4 + j;
                out[((size_t)(n * 8 + hd) * HW + s) * 16 + dd] = acc[i][j] + bv;
            }
        } else {
#pragma unroll
            for (int j = 0; j < 4; ++j)
                out[(size_t)(n * 128 + co) * HW + s0 + sp_grp * 4 + j] = acc[i][j] + bv;
        }
    }
}

// ---------------------------------------------------------------------------
// Deformable attention. grid: (400, 8, 4), block 256 = 16 sites x 16 ch.
// v_s [nb][s][16] fp32; offs NHWC fp32 [n][s'][128]; att NCHW fp32.
// ---------------------------------------------------------------------------
__global__ __launch_bounds__(256) void deform_attn_kernel(
    const float* __restrict__ v_s, const float* __restrict__ offs,
    const float* __restrict__ ref, float* __restrict__ att) {
    const int n = blockIdx.z, hd = blockIdx.y;
    const int s = blockIdx.x * 16 + (threadIdx.x >> 4);
    const int d = threadIdx.x & 15;
    const int nb = n * 8 + hd;

    const float cv = v_s[((size_t)nb * HW + s) * 16 + d];
    const float rx = ref[(size_t)(n * HW + s) * 2 + 0] * 80.f - 0.5f;
    const float ry = ref[(size_t)(n * HW + s) * 2 + 1] * 80.f - 0.5f;

    const int e = (s >= 3200) ? 1 : 0;
    const float* ob0 = offs + ((size_t)n * HW + (2 * s - e * HW)) * 128 + hd * 16 + e;

    float sampled[8], score[8];
#pragma unroll
    for (int p = 0; p < 8; ++p) {
        const float ox = ob0[2 * p];
        const float oy = ob0[128 + 2 * p];
        const float px = rx + ox;
        const float py = ry + oy;
        const float fx = floorf(px), fy = floorf(py);
        const int ix = (int)fx, iy = (int)fy;
        const float wx1 = px - fx, wy1 = py - fy;
        const float wx0 = 1.f - wx1, wy0 = 1.f - wy1;

        auto samp = [&](int xx, int yy) -> float {
            if (xx < 0 || xx >= Ww || yy < 0 || yy >= Hh) return 0.f;
            return v_s[((size_t)nb * HW + yy * Ww + xx) * 16 + d];
        };
        const float v00 = samp(ix, iy);
        const float v01 = samp(ix + 1, iy);
        const float v10 = samp(ix, iy + 1);
        const float v11 = samp(ix + 1, iy + 1);
        const float sv = v00 * (wx0 * wy0) + v01 * (wx1 * wy0) +
                         v10 * (wx0 * wy1) + v11 * (wx1 * wy1);
        sampled[p] = sv;
        float sc = sv * cv;
        sc += __shfl_xor(sc, 1);
        sc += __shfl_xor(sc, 2);
        sc += __shfl_xor(sc, 4);
        sc += __shfl_xor(sc, 8);
        score[p] = sc;
    }

    float m = score[0];
#pragma unroll
    for (int p = 1; p < 8; ++p) m = fmaxf(m, score[p]);
    float sum = 0.f, aw[8];
#pragma unroll
    for (int p = 0; p < 8; ++p) {
        aw[p] = __expf(score[p] - m);
        sum += aw[p];
    }
    const float inv = 1.f / sum;
    float o = 0.f;
#pragma unroll
    for (int p = 0; p < 8; ++p) o += aw[p] * sampled[p];
    o *= inv;

    att[(size_t)(n * 128 + hd * 16 + d) * HW + s] = o;
}

// ---------------------------------------------------------------------------
extern "C" void kernel_launch(void* const* d_in, const int* in_sizes, int n_in,
                              void* d_out, int out_size, void* d_ws, size_t ws_size,
                              hipStream_t stream) {
    const float* query = (const float*)d_in[0];
    const float* value = (const float*)d_in[1];
    const float* ref   = (const float*)d_in[2];
    const float* co_w1 = (const float*)d_in[3];
    const float* co_b1 = (const float*)d_in[4];
    const float* co_w2 = (const float*)d_in[5];
    const float* co_b2 = (const float*)d_in[6];
    const float* co_w3 = (const float*)d_in[7];
    const float* co_b3 = (const float*)d_in[8];
    const float* co_w4 = (const float*)d_in[9];
    const float* co_b4 = (const float*)d_in[10];
    const float* val_w = (const float*)d_in[11];
    const float* val_b = (const float*)d_in[12];
    const float* out_w = (const float*)d_in[13];
    const float* out_b = (const float*)d_in[14];

    char* ws = (char*)d_ws;
    size_t o = 0;
    auto alloc = [&](size_t bytes) { char* p = ws + o; o += (bytes + 255) & ~(size_t)255; return p; };

    _Float16* wb2 = (_Float16*)alloc(147456 * 2);
    _Float16* wb3 = (_Float16*)alloc(147456 * 2);
    _Float16* wb4 = (_Float16*)alloc(147456 * 2);
    float* wtv = (float*)alloc(16384 * 4);
    float* wto = (float*)alloc(16384 * 4);
    float* v_s = (float*)alloc(3276800 * 4);
    float* o4  = (float*)alloc(3276800 * 4);   // fp32 NHWC [4][6400][128]
    _Float16* wb1 = (_Float16*)o4;             // alias: wb1 used before o4 written
    char* hRegion = alloc(3276800 * 4);
    _Float16* hA = (_Float16*)hRegion;                  // fp16 NHWC [4][6400][128]
    _Float16* hB = (_Float16*)(hRegion + 3276800 * 2);
    float* att = (float*)hRegion;              // alias: used after hA/hB dead

    // weight packing
    wblob_kernel<<<(294912 + 255) / 256, 256, 0, stream>>>(co_w1, wb1, 256);
    wblob_kernel<<<(147456 + 255) / 256, 256, 0, stream>>>(co_w2, wb2, 128);
    wblob_kernel<<<(147456 + 255) / 256, 256, 0, stream>>>(co_w3, wb3, 128);
    wblob_kernel<<<(147456 + 255) / 256, 256, 0, stream>>>(co_w4, wb4, 128);
    wt_kernel<<<(16384 + 255) / 256, 256, 0, stream>>>(val_w, wtv, 128, 128, 1);
    wt_kernel<<<(16384 + 255) / 256, 256, 0, stream>>>(out_w, wto, 128, 128, 1);

    // v = 1x1 conv(value) -> v_s (NHWC-16 fp32)
    conv1x1_kernel<0><<<dim3(100, NB), 256, 0, stream>>>(value, wtv, val_b, v_s);

    // offset conv stack (MFMA fp16)
    conv3x3_mfma<256, 1, true ><<<dim3(100, 2, NB), 256, 0, stream>>>(query, wb1, co_b1, hA);
    conv3x3_mfma<128, 1, false><<<dim3(100, 2, NB), 256, 0, stream>>>(hA, wb2, co_b2, hB);
    conv3x3_mfma<128, 1, false><<<dim3(100, 2, NB), 256, 0, stream>>>(hB, wb3, co_b3, hA);
    conv3x3_mfma<128, 2, false><<<dim3(100, 2, NB), 256, 0, stream>>>(hA, wb4, co_b4, o4);

    // deformable attention -> att (NCHW fp32)
    deform_attn_kernel<<<dim3(400, 8, NB), 256, 0, stream>>>(v_s, o4, ref, att);

    // final 1x1 conv -> d_out (NCHW fp32)
    conv1x1_kernel<1><<<dim3(100, NB), 256, 0, stream>>>(att, wto, out_b, (float*)d_out);
}

// Round 3
// 337.702 us; speedup vs baseline: 2.9028x; 1.2668x over previous
//
#include <hip/hip_runtime.h>
#include <math.h>

#define Hh 80
#define Ww 80
#define HW 6400
#define NB 4

typedef _Float16 half8 __attribute__((ext_vector_type(8)));
typedef _Float16 half4v __attribute__((ext_vector_type(4)));
typedef float f32x16 __attribute__((ext_vector_type(16)));

// ---------------------------------------------------------------------------
// Weight transpose for 1x1 convs: OIHW -> [ci][co]
// ---------------------------------------------------------------------------
__global__ void wt_kernel(const float* __restrict__ src, float* __restrict__ dst,
                          int CO, int CI, int taps) {
    int idx = blockIdx.x * 256 + threadIdx.x;
    int total = CO * CI * taps;
    if (idx >= total) return;
    int co = idx % CO;
    int kt = idx / CO;
    int t  = kt % taps;
    int ci = kt / taps;
    dst[idx] = src[(co * CI + ci) * taps + t];
}

// ---------------------------------------------------------------------------
// Pack conv weights OIHW fp32 -> fp16 MFMA A-fragment blob:
// flat = ((((CT*NC + c)*taps + tap)*2 + h)*64 + lane)*8 + j
//   co = CT*32 + (lane&31);  ci = c*32 + h*16 + (lane>>5)*8 + j
// ---------------------------------------------------------------------------
__global__ void wblob_kernel(const float* __restrict__ src, _Float16* __restrict__ dst,
                             int CI, int taps) {
    int d = blockIdx.x * 256 + threadIdx.x;
    int NC = CI / 32;
    int total = 128 * CI * taps;
    if (d >= total) return;
    int j = d & 7;
    int l = (d >> 3) & 63;
    int h = (d >> 9) & 1;
    int rest = d >> 10;
    int tap = rest % taps;
    rest /= taps;
    int c = rest % NC;
    int CT = rest / NC;
    int co = CT * 32 + (l & 31);
    int ci = c * 32 + h * 16 + (l >> 5) * 8 + j;
    dst[d] = (_Float16)src[((size_t)co * CI + ci) * taps + tap];
}

// ---------------------------------------------------------------------------
// fp32 NCHW -> fp16 NHWC transpose. grid (100, N), block 256, 64-site tiles.
// ---------------------------------------------------------------------------
template <int CI>
__global__ __launch_bounds__(256) void nchw_to_nhwc_h(
    const float* __restrict__ in, _Float16* __restrict__ out) {
    const int n = blockIdx.y, s0 = blockIdx.x * 64;
    const int t = threadIdx.x;
    constexpr int ST = CI + 8;
    __shared__ _Float16 T[64 * ST];
    for (int idx = t; idx < 64 * CI; idx += 256) {
        int ci = idx >> 6, sl = idx & 63;
        T[sl * ST + ci] = (_Float16)in[((size_t)n * CI + ci) * HW + s0 + sl];
    }
    __syncthreads();
    constexpr int NQ = CI / 8;
    for (int idx = t; idx < 64 * NQ; idx += 256) {
        int q = idx % NQ, sl = idx / NQ;
        *(int4*)(out + ((size_t)n * HW + s0 + sl) * CI + q * 8) =
            *(const int4*)(&T[sl * ST + q * 8]);
    }
}

// ---------------------------------------------------------------------------
// MFMA implicit-GEMM 3x3 conv, pad=1, fp16 NHWC in.
// Block 256 = 4 waves; block tile = 128co x 64sp (8x8 2D region).
// Wave = 64co (2 co-tiles, B-frag reuse x2) x 32sp (8x4).
// Double-buffered LDS halo staging (10x10 sites x 32 ci per chunk).
// grid: (10, 10, N).  ACT 1: leaky -> fp16 NHWC.  ACT 2: 10*tanh -> fp32 NHWC.
// ---------------------------------------------------------------------------
template <int CI, int ACT>
__global__ __launch_bounds__(256) void conv3x3_mfma(
    const _Float16* __restrict__ in, const _Float16* __restrict__ wblob,
    const float* __restrict__ bias, void* __restrict__ outp) {
    const int x0 = blockIdx.x * 8, y0 = blockIdx.y * 8, n = blockIdx.z;
    const int t = threadIdx.x;
    const int w = t >> 6, l = t & 63;
    const int cw = w >> 1, sh = w & 1;
    const int lane31 = l & 31, lhalf = l >> 5;
    const int lx = lane31 & 7, ly = lane31 >> 3;

    constexpr int NC = CI / 32;
    __shared__ _Float16 Bs[2][100 * 40];

    const int gy = y0 + sh * 4 + ly, gx = x0 + lx;
    const int s = gy * 80 + gx;

    f32x16 acc0 = {}, acc1 = {};
    const int CT0 = cw * 2, CT1 = cw * 2 + 1;

    auto load_chunk = [&](int c, int4* r) {
#pragma unroll
        for (int k = 0; k < 2; ++k) {
            int idx = t + k * 256;
            int4 v = {0, 0, 0, 0};
            if (idx < 400) {
                int site = idx >> 2, q = idx & 3;
                int hy = site / 10, hx = site - hy * 10;
                int yy = y0 - 1 + hy, xx = x0 - 1 + hx;
                if (yy >= 0 && yy < Hh && xx >= 0 && xx < Ww)
                    v = *(const int4*)(in + (((size_t)n * HW + yy * 80 + xx) * CI + c * 32 + q * 8));
            }
            r[k] = v;
        }
    };
    auto write_chunk = [&](int buf, const int4* r) {
#pragma unroll
        for (int k = 0; k < 2; ++k) {
            int idx = t + k * 256;
            if (idx < 400) {
                int site = idx >> 2, q = idx & 3;
                *(int4*)&Bs[buf][site * 40 + q * 8] = r[k];
            }
        }
    };

    int4 r[2];
    load_chunk(0, r);
    write_chunk(0, r);
    __syncthreads();

    for (int c = 0; c < NC; ++c) {
        if (c + 1 < NC) load_chunk(c + 1, r);
        const _Float16* w0 = wblob + ((size_t)(CT0 * NC + c) * 18) * 512 + l * 8;
        const _Float16* w1 = wblob + ((size_t)(CT1 * NC + c) * 18) * 512 + l * 8;
        const _Float16* bp = &Bs[c & 1][0];
#pragma unroll
        for (int tap = 0; tap < 9; ++tap) {
            const int dy = tap / 3, dx = tap % 3;
            const _Float16* brow = bp + ((sh * 4 + ly + dy) * 10 + (lx + dx)) * 40;
#pragma unroll
            for (int h = 0; h < 2; ++h) {
                half8 a0 = *(const half8*)(w0 + (tap * 2 + h) * 512);
                half8 a1 = *(const half8*)(w1 + (tap * 2 + h) * 512);
                half8 b = *(const half8*)(brow + h * 16 + lhalf * 8);
                acc0 = __builtin_amdgcn_mfma_f32_32x32x16_f16(a0, b, acc0, 0, 0, 0);
                acc1 = __builtin_amdgcn_mfma_f32_32x32x16_f16(a1, b, acc1, 0, 0, 0);
            }
        }
        if (c + 1 < NC) write_chunk((c + 1) & 1, r);
        __syncthreads();
    }

    // epilogue: D col(sp)=lane&31, row(co)=(reg&3)+8*(reg>>2)+4*(lane>>5)
    const size_t rowbase = ((size_t)n * HW + s) * 128;
#pragma unroll
    for (int ct = 0; ct < 2; ++ct) {
        const f32x16& acc = ct ? acc1 : acc0;
        const int co_base = (cw * 2 + ct) * 32;
#pragma unroll
        for (int q = 0; q < 4; ++q) {
            const int co0 = co_base + 8 * q + 4 * lhalf;
            float v[4];
#pragma unroll
            for (int i = 0; i < 4; ++i) {
                float vv = acc[q * 4 + i] + bias[co0 + i];
                if (ACT == 1) vv = (vv >= 0.f) ? vv : 0.1f * vv;
                else vv = 10.f * tanhf(vv);
                v[i] = vv;
            }
            if (ACT == 1) {
                half4v hv = {(_Float16)v[0], (_Float16)v[1], (_Float16)v[2], (_Float16)v[3]};
                *(half4v*)((_Float16*)outp + rowbase + co0) = hv;
            } else {
                float4 fv = {v[0], v[1], v[2], v[3]};
                *(float4*)((float*)outp + rowbase + co0) = fv;
            }
        }
    }
}

// ---------------------------------------------------------------------------
// 1x1 conv (fp32 GEMM 128x128 over spatial). grid: (100, N), block 256.
// wt layout: [ci][128co]. MODE 0: write v_s NHWC-16; MODE 1: write NCHW.
// ---------------------------------------------------------------------------
template <int MODE>
__global__ __launch_bounds__(256) void conv1x1_kernel(
    const float* __restrict__ in, const float* __restrict__ wt,
    const float* __restrict__ bias, float* __restrict__ out) {
    const int n = blockIdx.y;
    const int s0 = blockIdx.x * 64;
    const int t = threadIdx.x;
    const int sp_grp = t & 15;
    const int co_grp = t >> 4;

    __shared__ float Wl[16 * 128];
    __shared__ float Il[16 * 64];

    float acc[8][4];
#pragma unroll
    for (int i = 0; i < 8; ++i)
#pragma unroll
        for (int j = 0; j < 4; ++j) acc[i][j] = 0.f;

    for (int ch = 0; ch < 8; ++ch) {
        const int ci0 = ch * 16;
        __syncthreads();
        for (int i = t; i < 16 * 128; i += 256) Wl[i] = wt[ci0 * 128 + i];
        for (int i = t; i < 16 * 64; i += 256) {
            int ci = i >> 6, sp = i & 63;
            Il[i] = in[(size_t)(n * 128 + ci0 + ci) * HW + s0 + sp];
        }
        __syncthreads();
#pragma unroll
        for (int ci = 0; ci < 16; ++ci) {
            float4 a0 = *(const float4*)&Wl[ci * 128 + co_grp * 8];
            float4 a1 = *(const float4*)&Wl[ci * 128 + co_grp * 8 + 4];
            float4 b  = *(const float4*)&Il[ci * 64 + sp_grp * 4];
            float av[8] = {a0.x, a0.y, a0.z, a0.w, a1.x, a1.y, a1.z, a1.w};
            float bv[4] = {b.x, b.y, b.z, b.w};
#pragma unroll
            for (int i = 0; i < 8; ++i)
#pragma unroll
                for (int j = 0; j < 4; ++j)
                    acc[i][j] = fmaf(av[i], bv[j], acc[i][j]);
        }
    }

#pragma unroll
    for (int i = 0; i < 8; ++i) {
        const int co = co_grp * 8 + i;
        const float bv = bias[co];
        if (MODE == 0) {
            const int hd = co >> 4, dd = co & 15;
#pragma unroll
            for (int j = 0; j < 4; ++j) {
                int s = s0 + sp_grp * 4 + j;
                out[((size_t)(n * 8 + hd) * HW + s) * 16 + dd] = acc[i][j] + bv;
            }
        } else {
#pragma unroll
            for (int j = 0; j < 4; ++j)
                out[(size_t)(n * 128 + co) * HW + s0 + sp_grp * 4 + j] = acc[i][j] + bv;
        }
    }
}

// ---------------------------------------------------------------------------
// Deformable attention. grid: (400, 8, 4), block 256 = 16 sites x 16 ch.
// v_s [nb][s][16] fp32; offs NHWC fp32 [n][s'][128]; att NCHW fp32.
// ---------------------------------------------------------------------------
__global__ __launch_bounds__(256) void deform_attn_kernel(
    const float* __restrict__ v_s, const float* __restrict__ offs,
    const float* __restrict__ ref, float* __restrict__ att) {
    const int n = blockIdx.z, hd = blockIdx.y;
    const int s = blockIdx.x * 16 + (threadIdx.x >> 4);
    const int d = threadIdx.x & 15;
    const int nb = n * 8 + hd;

    const float cv = v_s[((size_t)nb * HW + s) * 16 + d];
    const float rx = ref[(size_t)(n * HW + s) * 2 + 0] * 80.f - 0.5f;
    const float ry = ref[(size_t)(n * HW + s) * 2 + 1] * 80.f - 0.5f;

    const int e = (s >= 3200) ? 1 : 0;
    const float* ob0 = offs + ((size_t)n * HW + (2 * s - e * HW)) * 128 + hd * 16 + e;

    float sampled[8], score[8];
#pragma unroll
    for (int p = 0; p < 8; ++p) {
        const float ox = ob0[2 * p];
        const float oy = ob0[128 + 2 * p];
        const float px = rx + ox;
        const float py = ry + oy;
        const float fx = floorf(px), fy = floorf(py);
        const int ix = (int)fx, iy = (int)fy;
        const float wx1 = px - fx, wy1 = py - fy;
        const float wx0 = 1.f - wx1, wy0 = 1.f - wy1;

        auto samp = [&](int xx, int yy) -> float {
            if (xx < 0 || xx >= Ww || yy < 0 || yy >= Hh) return 0.f;
            return v_s[((size_t)nb * HW + yy * Ww + xx) * 16 + d];
        };
        const float v00 = samp(ix, iy);
        const float v01 = samp(ix + 1, iy);
        const float v10 = samp(ix, iy + 1);
        const float v11 = samp(ix + 1, iy + 1);
        const float sv = v00 * (wx0 * wy0) + v01 * (wx1 * wy0) +
                         v10 * (wx0 * wy1) + v11 * (wx1 * wy1);
        sampled[p] = sv;
        float sc = sv * cv;
        sc += __shfl_xor(sc, 1);
        sc += __shfl_xor(sc, 2);
        sc += __shfl_xor(sc, 4);
        sc += __shfl_xor(sc, 8);
        score[p] = sc;
    }

    float m = score[0];
#pragma unroll
    for (int p = 1; p < 8; ++p) m = fmaxf(m, score[p]);
    float sum = 0.f, aw[8];
#pragma unroll
    for (int p = 0; p < 8; ++p) {
        aw[p] = __expf(score[p] - m);
        sum += aw[p];
    }
    const float inv = 1.f / sum;
    float o = 0.f;
#pragma unroll
    for (int p = 0; p < 8; ++p) o += aw[p] * sampled[p];
    o *= inv;

    att[(size_t)(n * 128 + hd * 16 + d) * HW + s] = o;
}

// ---------------------------------------------------------------------------
extern "C" void kernel_launch(void* const* d_in, const int* in_sizes, int n_in,
                              void* d_out, int out_size, void* d_ws, size_t ws_size,
                              hipStream_t stream) {
    const float* query = (const float*)d_in[0];
    const float* value = (const float*)d_in[1];
    const float* ref   = (const float*)d_in[2];
    const float* co_w1 = (const float*)d_in[3];
    const float* co_b1 = (const float*)d_in[4];
    const float* co_w2 = (const float*)d_in[5];
    const float* co_b2 = (const float*)d_in[6];
    const float* co_w3 = (const float*)d_in[7];
    const float* co_b3 = (const float*)d_in[8];
    const float* co_w4 = (const float*)d_in[9];
    const float* co_b4 = (const float*)d_in[10];
    const float* val_w = (const float*)d_in[11];
    const float* val_b = (const float*)d_in[12];
    const float* out_w = (const float*)d_in[13];
    const float* out_b = (const float*)d_in[14];

    char* ws = (char*)d_ws;
    size_t o = 0;
    auto alloc = [&](size_t bytes) { char* p = ws + o; o += (bytes + 255) & ~(size_t)255; return p; };

    _Float16* wb2 = (_Float16*)alloc(147456 * 2);
    _Float16* wb3 = (_Float16*)alloc(147456 * 2);
    _Float16* wb4 = (_Float16*)alloc(147456 * 2);
    float* wtv = (float*)alloc(16384 * 4);
    float* wto = (float*)alloc(16384 * 4);
    char* vsR = alloc(3276800 * 4);            // v_s fp32 [32][6400][16]
    float* v_s = (float*)vsR;
    _Float16* wb1 = (_Float16*)vsR;            // alias: wb1 dead before v_s written
    char* R1 = alloc(3276800 * 4);
    _Float16* q_h = (_Float16*)R1;             // fp16 NHWC [4][6400][256] (13.1 MB)
    float* o4 = (float*)R1;                    // fp32 NHWC [4][6400][128]; q_h dead
    char* R2 = alloc(3276800 * 4);
    _Float16* hA = (_Float16*)R2;              // fp16 NHWC [4][6400][128]
    _Float16* hB = (_Float16*)(R2 + 3276800 * 2);
    float* att = (float*)R2;                   // alias: used after hA/hB dead

    // prep: transpose query, pack weights
    nchw_to_nhwc_h<256><<<dim3(100, NB), 256, 0, stream>>>(query, q_h);
    wblob_kernel<<<(294912 + 255) / 256, 256, 0, stream>>>(co_w1, wb1, 256, 9);
    wblob_kernel<<<(147456 + 255) / 256, 256, 0, stream>>>(co_w2, wb2, 128, 9);
    wblob_kernel<<<(147456 + 255) / 256, 256, 0, stream>>>(co_w3, wb3, 128, 9);
    wblob_kernel<<<(147456 + 255) / 256, 256, 0, stream>>>(co_w4, wb4, 128, 9);
    wt_kernel<<<(16384 + 255) / 256, 256, 0, stream>>>(val_w, wtv, 128, 128, 1);
    wt_kernel<<<(16384 + 255) / 256, 256, 0, stream>>>(out_w, wto, 128, 128, 1);

    // conv1 (must precede val-conv: wb1 aliases v_s region)
    conv3x3_mfma<256, 1><<<dim3(10, 10, NB), 256, 0, stream>>>(q_h, wb1, co_b1, hA);

    // v = 1x1 conv(value) -> v_s (NHWC-16 fp32)
    conv1x1_kernel<0><<<dim3(100, NB), 256, 0, stream>>>(value, wtv, val_b, v_s);

    // rest of offset conv stack
    conv3x3_mfma<128, 1><<<dim3(10, 10, NB), 256, 0, stream>>>(hA, wb2, co_b2, hB);
    conv3x3_mfma<128, 1><<<dim3(10, 10, NB), 256, 0, stream>>>(hB, wb3, co_b3, hA);
    conv3x3_mfma<128, 2><<<dim3(10, 10, NB), 256, 0, stream>>>(hA, wb4, co_b4, o4);

    // deformable attention -> att (NCHW fp32)
    deform_attn_kernel<<<dim3(400, 8, NB), 256, 0, stream>>>(v_s, o4, ref, att);

    // final 1x1 conv -> d_out (NCHW fp32)
    conv1x1_kernel<1><<<dim3(100, NB), 256, 0, stream>>>(att, wto, out_b, (float*)d_out);
}